// Round 6
// baseline (209.981 us; speedup 1.0000x reference)
//
#include <hip/hip_runtime.h>
#include <hip/hip_bf16.h>

// RGCN layer: out = relu(h@W0 + segment_sum(norm * h[src] @ W[rel], dst))
// R14 fused v8. Three dispatches: memset(cnt) -> k_prep -> k_fused.
// R5 post-mortem: register-occupancy theory DEAD (acc halved, occupancy
// unchanged 53.6%; per-SIMD pool 2048 regs never binds at ~70-90 regs).
// Invariant across v3/v6/v7: ~2 resident 8-wave blocks, ~72us. Best fit:
// schedulable LDS ~128KB (48KB -> 2 blocks) + coarse 8-wave granule.
// v8: BN=16 nodes/block, 24KB LDS, 6250 blocks. Thread limit (2048/512=4
// blocks) binds before LDS (96KB<=128) -> up to 32 waves/CU. Phase 1: one
// pass, 2 nodes/wave (v7's 32-lane layout, acc[5][4]). Phase 2: wave wv ->
// col-tile wv, single 16-row tile, 24 MFMA, cacc=4. Swizzles unchanged.
// Cost accepted: Bt L2 traffic 2x (1.22GB aggregate).
// Tripwires: Occupancy >=85 = theory confirmed; ~50 = hidden per-block cap
// -> pivot to relation-FMA-waste cut; occupancy up + dur flat = L2-bound.

#define NN   100000
#define NE   600000
#define FEAT 128
#define RNUM 5
#define CAP  32    // edge bucket capacity; P(deg>=32)~1e-12 per node (passed R7)
#define KC   24    // k-chunks of 32 (5*128 rel + 128 identity = 768)
#define BN   16    // nodes per block

#define SCAT_B 2344            // ceil(NE/256)
#define PREP_T (NN * 32 + FEAT * KC * 32)
#define PREP_B ((PREP_T + 255) / 256)

typedef __attribute__((ext_vector_type(8))) short short8;
typedef __attribute__((ext_vector_type(4))) float float4v;

static __device__ __forceinline__ unsigned short f2bf(float x) {
  union { float f; unsigned u; } v; v.f = x;
  unsigned r = v.u + 0x7FFFu + ((v.u >> 16) & 1u);  // RNE
  return (unsigned short)(r >> 16);
}

// ---- merged: edge->bucket scatter + (h -> bf16 hb, frag-linear bf16 Bt) -----
// Bt granule g = (c*8+n0)*64+ln (16B, j=0..7) holds B[k][o] for
// o = n0*16+(ln&15), k = c*32+((ln>>4)<<3)+j  (c = 0..23).
__global__ void k_prep(const int* __restrict__ src, const int* __restrict__ dst,
                       const int* __restrict__ eid, const float* __restrict__ norm,
                       const float* __restrict__ h, const float* __restrict__ weight,
                       const float* __restrict__ W0, int* __restrict__ cnt,
                       int2* __restrict__ s_edge, unsigned short* __restrict__ hb,
                       unsigned short* __restrict__ Bt) {
  int bid = blockIdx.x;
  if (bid < SCAT_B) {
    int e = bid * 256 + threadIdx.x;
    if (e < NE) {
      int d = dst[e];
      int p = atomicAdd(&cnt[d], 1);
      if (p < CAP) {
        union { float f; int i; } nb; nb.f = norm[e];
        s_edge[(size_t)d * CAP + p] = make_int2(src[e] | (eid[e] << 20), nb.i);
      }
    }
  } else {
    int t = (bid - SCAT_B) * 256 + threadIdx.x;
    if (t < NN * 32) {                   // 4 h-elements per thread
      float4v v = *(const float4v*)(h + (size_t)t * 4);
      unsigned long long p = (unsigned long long)f2bf(v[0])
                           | ((unsigned long long)f2bf(v[1]) << 16)
                           | ((unsigned long long)f2bf(v[2]) << 32)
                           | ((unsigned long long)f2bf(v[3]) << 48);
      *(unsigned long long*)(hb + (size_t)t * 4) = p;
    } else {
      int u = t - NN * 32;
      if (u < FEAT * KC * 32) {
        int j = u & 7, g = u >> 3;
        int ln = g & 63, n0 = (g >> 6) & 7, c = g >> 9;
        int o = n0 * 16 + (ln & 15);
        int k = c * 32 + ((ln >> 4) << 3) + j;
        float v = (k < 640) ? weight[(k >> 7) * 16384 + (k & 127) * 128 + o]
                            : W0[(k - 640) * 128 + o];
        Bt[u] = f2bf(v);
      }
    }
  }
}

// 32-lane-per-node accumulate: lane holds 4 feats (one uint2 of bf16x4)
static __device__ __forceinline__ void accum_edge(float acc[RNUM][4], int ex,
                                                  int ey, uint2 v) {
  union { int i; float f; } nb; nb.i = ey;
  int r = ex >> 20;
  float nm[RNUM];
#pragma unroll
  for (int rr = 0; rr < RNUM; ++rr) nm[rr] = (r == rr) ? nb.f : 0.f;
  float f[4];
  {
    union { unsigned u; float g; } lo, hi;
    lo.u = v.x << 16; hi.u = v.x & 0xFFFF0000u; f[0] = lo.g; f[1] = hi.g;
    lo.u = v.y << 16; hi.u = v.y & 0xFFFF0000u; f[2] = lo.g; f[3] = hi.g;
  }
#pragma unroll
  for (int rr = 0; rr < RNUM; ++rr)
#pragma unroll
    for (int i = 0; i < 4; ++i) acc[rr][i] += nm[rr] * f[i];
}

// ---- FUSED aggregate + GEMM -------------------------------------------------
// Block = 512 (8 waves), 16 nodes/block (6250 blocks; 16*6250 = 100000 exact).
// Phase 1: wave wv owns nodes base+wv*2+{0,1} (g2 = lane>>5 picks node);
//   lane t2 = lane&31 holds feats t2*4..t2*4+3; uint2 gathers (256B/row).
//   acc[5][4]; descriptor prefetch (v6). Results + identity -> 24KB LDS,
//   XOR-swizzled ds_write_b64.
// Phase 2 (one barrier): wave wv -> out-col tile n0 = wv, single 16-row
//   tile, 24 MFMA; A-frags via swizzled ds_read_b128 (conflict-free);
//   B-frags from frag-linear Bt in L2, each granule read once per block.
// Epilogue: relu'd C via LDS fp32 [16][132] -> full-line 512B row stores.
__global__ __launch_bounds__(512, 8) void k_fused(
    const unsigned short* __restrict__ hb, const int* __restrict__ cnt,
    const int2* __restrict__ s_edge, const unsigned short* __restrict__ Bt,
    float* __restrict__ out) {
  __shared__ uint4 Atile[KC * 64];       // 24 chunks x 64 granules x 16B = 24KB
  int tid = threadIdx.x;
  int wv = tid >> 6, lane = tid & 63;
  int base = blockIdx.x * BN;
  uint2* Aw2 = (uint2*)Atile;
  const uint2* hb2 = (const uint2*)hb;

  // ---- phase 1: one pass; 2 nodes per wave, 32 lanes per node
  int g2 = lane >> 5, t2 = lane & 31;
  int cB = t2 >> 3, kk = (t2 >> 1) & 3, par = t2 & 1;
  int node = base + wv * 2 + g2;         // always < NN (exact division)
  int row = wv * 2 + g2;                 // 0..15
  int glen = cnt[node]; if (glen > CAP) glen = CAP;
  const int4* ep4 = (const int4*)(s_edge + (size_t)node * CAP);
  uint2 idv = hb2[(size_t)node * 32 + t2];  // identity feats, off crit path
  float acc[RNUM][4] = {};
  int npair = glen >> 1;
  int4 d = (glen > 0) ? ep4[0] : make_int4(0, 0, 0, 0);
  for (int p = 0; p < npair; ++p) {
    int4 dn = ep4[p + 1];                // prefetch next pair (pad-safe)
    uint2 v0 = hb2[(d.x & 0xFFFFF) * 32 + t2];
    uint2 v1 = hb2[(d.z & 0xFFFFF) * 32 + t2];
    accum_edge(acc, d.x, d.y, v0);
    accum_edge(acc, d.z, d.w, v1);
    d = dn;
  }
  if (glen & 1) {                        // edge 2*npair is d.x of prefetched d
    uint2 v = hb2[(d.x & 0xFFFFF) * 32 + t2];
    accum_edge(acc, d.x, d.y, v);
  }
  // LDS writes (b64): granule sidx = c*64 + kk*16 + (row ^ ((c*4+kk)&7)),
  // even t2 -> bytes 0-7 (k0..k0+3), odd t2 -> bytes 8-15 (k0+4..k0+7).
#pragma unroll
  for (int rr = 0; rr < RNUM; ++rr) {
    int c = rr * 4 + cB;
    uint2 pk;
    pk.x = (unsigned)f2bf(acc[rr][0]) | ((unsigned)f2bf(acc[rr][1]) << 16);
    pk.y = (unsigned)f2bf(acc[rr][2]) | ((unsigned)f2bf(acc[rr][3]) << 16);
    int sidx = c * 64 + kk * 16 + (row ^ ((c * 4 + kk) & 7));
    Aw2[sidx * 2 + par] = pk;
  }
  {   // identity chunk: feats t2*4..t2*4+3 -> c = 20+cB
    int c = 20 + cB;
    int sidx = c * 64 + kk * 16 + (row ^ ((c * 4 + kk) & 7));
    Aw2[sidx * 2 + par] = idv;
  }
  __syncthreads();

  // ---- phase 2: GEMM. Wave wv -> out-col tile n0 = wv, single row-tile.
  int m = lane & 15, qq = lane >> 4;
  float4v cacc = (float4v){0.f, 0.f, 0.f, 0.f};
#pragma unroll
  for (int c = 0; c < KC; ++c) {
    int sx = qq * 16 + (m ^ ((c * 4 + qq) & 7));
    short8 af = *(const short8*)&Atile[c * 64 + sx];
    short8 bf = *(const short8*)&Bt[((c * 8 + wv) * 64 + lane) * 8];
    cacc = __builtin_amdgcn_mfma_f32_16x16x32_bf16(af, bf, cacc, 0, 0, 0);
  }

  // ---- epilogue: relu -> LDS fp32 [16][132] -> coalesced full-line stores
  __syncthreads();                        // all waves done reading Atile
  float* Cs = (float*)Atile;              // 16*132*4 = 8.4KB <= 24KB
#pragma unroll
  for (int r = 0; r < 4; ++r) {
    float v = cacc[r];                    // C/D layout: col=m, row=qq*4+r [m89]
    Cs[(qq * 4 + r) * 132 + wv * 16 + m] = v > 0.f ? v : 0.f;
  }
  __syncthreads();
  int r0 = tid >> 5, c0 = (tid & 31) * 4; // wave writes 2 full 512B rows
  float4v w0 = *(const float4v*)&Cs[r0 * 132 + c0];
  *(float4v*)(out + (size_t)(base + r0) * FEAT + c0) = w0;
}

// ---- slow-but-correct fallback if ws_size is too small ----------------------
__global__ void k_slow_mm(const float* __restrict__ h, const float* __restrict__ W0,
                          float* __restrict__ out) {
  __shared__ float hn[128];
  int n = blockIdx.x, t = threadIdx.x;
  hn[t] = h[(size_t)n * 128 + t];
  __syncthreads();
  float a = 0.f;
  for (int i = 0; i < 128; ++i) a += hn[i] * W0[i * 128 + t];
  out[(size_t)n * 128 + t] = a;
}
__global__ void k_slow_edge(const float* __restrict__ h, const float* __restrict__ weight,
                            const float* __restrict__ norm, const int* __restrict__ src,
                            const int* __restrict__ dst, const int* __restrict__ eid,
                            float* __restrict__ out) {
  __shared__ float hs[128];
  int e = blockIdx.x, t = threadIdx.x;
  hs[t] = h[(size_t)src[e] * 128 + t];
  __syncthreads();
  const float* W = weight + (size_t)eid[e] * 16384;
  float a = 0.f;
  for (int i = 0; i < 128; ++i) a += hs[i] * W[i * 128 + t];
  atomicAdd(&out[(size_t)dst[e] * 128 + t], a * norm[e]);
}
__global__ void k_slow_relu(float* out) {
  int i = blockIdx.x * 256 + threadIdx.x;
  if (i < NN * FEAT) out[i] = fmaxf(out[i], 0.f);
}

extern "C" void kernel_launch(void* const* d_in, const int* in_sizes, int n_in,
                              void* d_out, int out_size, void* d_ws, size_t ws_size,
                              hipStream_t stream) {
  const float* h      = (const float*)d_in[0];
  const float* weight = (const float*)d_in[1];
  const float* W0     = (const float*)d_in[2];
  const float* norm   = (const float*)d_in[3];
  const int*   src    = (const int*)d_in[4];
  const int*   dst    = (const int*)d_in[5];
  const int*   eid    = (const int*)d_in[6];
  float* out = (float*)d_out;

  char* ws = (char*)d_ws;
  size_t off = 0;
  auto wsalloc = [&](size_t bytes) -> char* {
    char* p = ws + off;
    off += (bytes + 255) & ~(size_t)255;
    return p;
  };
  unsigned short* hb  = (unsigned short*)wsalloc((size_t)NN * FEAT * 2);  // 25.6 MB
  unsigned short* Bt  = (unsigned short*)wsalloc((size_t)FEAT * KC * 32 * 2);
  int*   cnt      = (int*)wsalloc((size_t)NN * 4);
  int2*  s_edge   = (int2*)wsalloc((size_t)NN * CAP * 8 + 256);           // 25.6 MB

  if (ws_size >= off) {
    hipMemsetAsync(cnt, 0, (size_t)NN * 4, stream);
    k_prep <<<SCAT_B + PREP_B, 256, 0, stream>>>(src, dst, eid, norm, h, weight,
                                                 W0, cnt, s_edge, hb, Bt);
    k_fused<<<NN / BN, 512, 0, stream>>>(hb, cnt, s_edge, Bt, out);
  } else {
    // workspace too small for the fast path: correct fallback
    k_slow_mm  <<<NN, 128, 0, stream>>>(h, W0, out);
    k_slow_edge<<<NE, 128, 0, stream>>>(h, weight, norm, src, dst, eid, out);
    k_slow_relu<<<(NN * FEAT + 255) / 256, 256, 0, stream>>>(out);
  }
}